// Round 18
// baseline (93.184 us; speedup 1.0000x reference)
//
#include <hip/hip_runtime.h>

// Fully-fused PINN-LISTA, transposed-MFMA + prep prefold + packed-f16 scan.
// R18 = R17 + glue elimination: h state IS the two f16x8 MFMA B-fragments
// (no hs2 array, no per-step union repack); elementwise pipeline runs on
// f16x8 vectors end-to-end; C-init via f32x4 elementwise fma (v_pk_fma_f32,
// no operand rebuild); s_setprio(1) around the MFMA cluster (independent
// unsynced waves -> m191 regime).

#define NB 32768
#define WIN 100
#define HH 64
#define AA 64
#define KITER 8
#define NAPPC 4
#define LNEPS 1e-5f
#define DTC 0.1f

// d_ws byte offsets
#define WS_WREC 0        // f16 [4][2][64][8]      = 8192 B   (A-slots, phi order)
#define WS_WE   8192     // f16 [8][4][4][64][8]   = 131072 B (K padded 100->128)
#define WS_WR   139264   // f16 [8][4][2][64][8]   = 65536 B
#define WS_WC   204800   // f32 [64]
#define WS_BC   205056   // f32 [64]
#define WS_DEC  205312   // f32 [64]
#define WS_LAM  205568   // f32 [8][64] -> ends 207616

typedef _Float16 f16x8 __attribute__((ext_vector_type(8)));
typedef _Float16 f16x4 __attribute__((ext_vector_type(4)));
typedef _Float16 f16x2v __attribute__((ext_vector_type(2)));
typedef __fp16 fp16x2 __attribute__((ext_vector_type(2)));
typedef float f32x4 __attribute__((ext_vector_type(4)));

union H4 { f16x4 v; fp16x2 h[2]; };
union HS8 { f16x2v p[4]; f16x8 v; };
union FD { f16x2v h; fp16x2 u; };

__device__ __forceinline__ float exp2_fast(float x) { return __builtin_amdgcn_exp2f(x); }
__device__ __forceinline__ float rsq_fast(float x) { return __builtin_amdgcn_rsqf(x); }
__device__ __forceinline__ float log2_fast(float x) { return __builtin_amdgcn_logf(x); }
__device__ __forceinline__ float softplus_fast(float x) {
  float ax = fabsf(x);
  float e = exp2_fast(-ax * 1.4426950408889634f);
  return fmaxf(x, 0.0f) + log2_fast(1.0f + e) * 0.6931471805599453f;
}
__device__ __forceinline__ f16x2v pk2(float a, float b) {
  FD t;
  t.u = __builtin_amdgcn_cvt_pkrtz(a, b);
  return t.h;
}
__device__ __forceinline__ f16x4 pack4(float a, float b, float c2, float d) {
  H4 t;
  t.h[0] = __builtin_amdgcn_cvt_pkrtz(a, b);
  t.h[1] = __builtin_amdgcn_cvt_pkrtz(c2, d);
  return t.v;
}
__device__ __forceinline__ f16x8 pack8(float a, float b, float c2, float d,
                                       float e, float f, float g2, float h) {
  HS8 t;
  t.p[0] = pk2(a, b);
  t.p[1] = pk2(c2, d);
  t.p[2] = pk2(e, f);
  t.p[3] = pk2(g2, h);
  return t.v;
}
__device__ __forceinline__ f16x8 bcast8(f16x2v x) {
  HS8 t;
  t.p[0] = x;
  t.p[1] = x;
  t.p[2] = x;
  t.p[3] = x;
  return t.v;
}
// cross-lane sum over lanes {i^16, i^32} (epilogue only)
__device__ __forceinline__ float xreduce(float q) {
  q += __shfl_xor(q, 16);
  q += __shfl_xor(q, 32);
  return q;
}

// ======================= prep kernel =======================
__global__ __launch_bounds__(256) void pinn_prep(
    const float* __restrict__ W_rec, const float* __restrict__ w_in,
    const float* __restrict__ b_in, const float* __restrict__ tau,
    const float* __restrict__ thr, const float* __restrict__ We,
    const float* __restrict__ Wr, char* __restrict__ ws) {
  _Float16* wrec16 = (_Float16*)(ws + WS_WREC);
  _Float16* we16 = (_Float16*)(ws + WS_WE);
  _Float16* wr16 = (_Float16*)(ws + WS_WR);
  float* wc = (float*)(ws + WS_WC);
  float* bc = (float*)(ws + WS_BC);
  float* dec = (float*)(ws + WS_DEC);
  float* lam = (float*)(ws + WS_LAM);
  const int tid = threadIdx.x, bid = blockIdx.x;
  if (bid == 0) {
    __shared__ float rm[64];
    if (tid < 64) {
      float s = 0.f;
      for (int m = 0; m < 64; ++m) s += W_rec[tid * 64 + m];
      rm[tid] = s * (1.f / 64.f);
    }
    __syncthreads();
    // wrec A-slots: idx = ((mt*2+kt)*64+l)*8+j
    for (int idx = tid; idx < 4096; idx += 256) {
      const int j = idx & 7, l = (idx >> 3) & 63, kt = (idx >> 9) & 1, mt = idx >> 10;
      const int g4 = ((l >> 4) << 2);
      const int k_in = kt * 32 + ((j < 4) ? (g4 + j) : (16 + g4 + (j - 4)));
      const int m = mt * 16 + (l & 15);
      wrec16[idx] = (_Float16)(W_rec[k_in * 64 + m] - rm[k_in]);
    }
    if (tid < 64) {
      float sw = 0.f, sb = 0.f;
      for (int i = 0; i < 64; ++i) { sw += w_in[i]; sb += b_in[i]; }
      wc[tid] = w_in[tid] - sw * (1.f / 64.f);
      bc[tid] = b_in[tid] - sb * (1.f / 64.f);
      dec[tid] = 1.f - DTC / softplus_fast(tau[tid]);
    }
    for (int i = tid; i < 512; i += 256) lam[i] = softplus_fast(thr[i]);
  } else {
    const int stride = (gridDim.x - 1) * 256;
    for (int i = (bid - 1) * 256 + tid; i < 65536 + 32768; i += stride) {
      if (i < 65536) {
        // we A-slots: i = (((k*4+mt)*4+kt)*64+l)*8+j
        const int j = i & 7, l = (i >> 3) & 63, kt = (i >> 9) & 3, mt = (i >> 11) & 3, k = i >> 13;
        const int g4 = ((l >> 4) << 2);
        const int t = kt * 32 + ((j < 4) ? (g4 + j) : (16 + g4 + (j - 4)));
        const int row = k * 64 + mt * 16 + (l & 15);
        we16[i] = (t < WIN) ? (_Float16)We[row * WIN + t] : (_Float16)0.f;
      } else {
        // wr A-slots: i2 = (((k*4+mt)*2+kt)*64+l)*8+j
        const int i2 = i - 65536;
        const int j = i2 & 7, l = (i2 >> 3) & 63, kt = (i2 >> 9) & 1, mt = (i2 >> 10) & 3, k = i2 >> 12;
        const int g4 = ((l >> 4) << 2);
        const int k_in = kt * 32 + ((j < 4) ? (g4 + j) : (16 + g4 + (j - 4)));
        const int row = k * 64 + mt * 16 + (l & 15);
        wr16[i2] = (_Float16)Wr[row * 64 + k_in];
      }
    }
  }
}

// ======================= main kernel =======================
__global__ __attribute__((amdgpu_flat_work_group_size(64, 64),
                          amdgpu_waves_per_eu(2, 2))) void pinn_fused(
    const float* __restrict__ y, const float* __restrict__ ln_w,
    const float* __restrict__ ln_b, const float* __restrict__ Wx0,
    const float* __restrict__ bx0, const float* __restrict__ be,
    const float* __restrict__ head_W, const float* __restrict__ head_b,
    const char* __restrict__ ws, float* __restrict__ out) {
  __shared__ float ybuf[16][101];  // (c*101)%32 all distinct -> conflict-free columns

  const _Float16* wrec16 = (const _Float16*)(ws + WS_WREC);
  const _Float16* we16 = (const _Float16*)(ws + WS_WE);
  const _Float16* wr16 = (const _Float16*)(ws + WS_WR);
  const float* wcp = (const float*)(ws + WS_WC);
  const float* bcp = (const float*)(ws + WS_BC);
  const float* decp = (const float*)(ws + WS_DEC);
  const float* lamp = (const float*)(ws + WS_LAM);

  const int l = threadIdx.x;
  const int c = l & 15;  // sample (C col / B col / A row)
  const int g = l >> 4;  // lane group
  const int s0 = blockIdx.x * 16;

  // ---- stage y tile ----
  for (int i = l; i < 16 * WIN; i += 64) {
    const int s = i / WIN;
    ybuf[s][i - s * WIN] = y[s0 * WIN + i];
  }

  // ---- per-H constants: bias f32x4 (packed C-init), LN/decay as f16x8 halves ----
  f32x4 wc4[4], bc4[4];
  f16x8 lnwA, lnwB, lnbA, lnbB, decA, decB;
  {
    HS8 lwA, lwB, lbA, lbB, dcA, dcB;
#pragma unroll
    for (int mt = 0; mt < 4; ++mt) {
      const int hb4 = mt * 16 + g * 4;
      const float4 wi = *(const float4*)&wcp[hb4];
      const float4 bi = *(const float4*)&bcp[hb4];
      const float4 lw = *(const float4*)&ln_w[hb4];
      const float4 lb = *(const float4*)&ln_b[hb4];
      const float4 dc = *(const float4*)&decp[hb4];
      wc4[mt] = (f32x4){wi.x, wi.y, wi.z, wi.w};
      bc4[mt] = (f32x4){bi.x, bi.y, bi.z, bi.w};
      HS8* lwD = (mt < 2) ? &lwA : &lwB;
      HS8* lbD = (mt < 2) ? &lbA : &lbB;
      HS8* dcD = (mt < 2) ? &dcA : &dcB;
      const int o = (mt & 1) * 2;
      lwD->p[o] = pk2(lw.x, lw.y);
      lwD->p[o + 1] = pk2(lw.z, lw.w);
      lbD->p[o] = pk2(lb.x, lb.y);
      lbD->p[o + 1] = pk2(lb.z, lb.w);
      dcD->p[o] = pk2(dc.x, dc.y);
      dcD->p[o + 1] = pk2(dc.z, dc.w);
    }
    lnwA = lwA.v; lnwB = lwB.v;
    lnbA = lbA.v; lnbB = lbB.v;
    decA = dcA.v; decB = dcB.v;
  }

  // ---- centered W' A-fragments (K=32 slot order) ----
  f16x8 wrec32[4][2];
#pragma unroll
  for (int mt = 0; mt < 4; ++mt)
#pragma unroll
    for (int kt = 0; kt < 2; ++kt)
      wrec32[mt][kt] = *(const f16x8*)&wrec16[((mt * 2 + kt) * 64 + l) * 8];

  __syncthreads();  // ybuf ready

  // h state IS the two B-fragments
  f16x8 hbA = pack8(0.f, 0.f, 0.f, 0.f, 0.f, 0.f, 0.f, 0.f);
  f16x8 hbB = hbA;
  const float inv64 = 1.0f / 64.0f;

  // Pade (1/16-scaled) / clamp constants (f16x8) + ones A-fragment
  const f16x8 cNq8 = pack8(0.00625f, 0.00625f, 0.00625f, 0.00625f, 0.00625f, 0.00625f, 0.00625f, 0.00625f);
  const f16x8 cNl8 = pack8(0.09375f, 0.09375f, 0.09375f, 0.09375f, 0.09375f, 0.09375f, 0.09375f, 0.09375f);
  const f16x8 cDq8 = pack8(0.375f, 0.375f, 0.375f, 0.375f, 0.375f, 0.375f, 0.375f, 0.375f);
  const f16x8 cDl8 = pack8(0.9375f, 0.9375f, 0.9375f, 0.9375f, 0.9375f, 0.9375f, 0.9375f, 0.9375f);
  const f16x8 cP8 = pack8(0.1f, 0.1f, 0.1f, 0.1f, 0.1f, 0.1f, 0.1f, 0.1f);
  const f16x8 cM8 = pack8(-0.1f, -0.1f, -0.1f, -0.1f, -0.1f, -0.1f, -0.1f, -0.1f);
  const f16x8 ones8 = pack8(1.f, 1.f, 1.f, 1.f, 1.f, 1.f, 1.f, 1.f);

  // ================= Phase 1: 100-step scan =================
  float xt = ybuf[c][0];
#pragma unroll 4
  for (int t = 0; t < WIN; ++t) {
    const float xtn = ybuf[c][t + 1];  // col 100 in-bounds (padded), unused at t=99
    const f32x4 xt4 = {xt, xt, xt, xt};
    f32x4 acc[4];
    __builtin_amdgcn_s_setprio(1);
#pragma unroll
    for (int mt = 0; mt < 4; ++mt) {
      f32x4 a = __builtin_elementwise_fma(xt4, wc4[mt], bc4[mt]);
      a = __builtin_amdgcn_mfma_f32_16x16x32_f16(wrec32[mt][0], hbA, a, 0, 0, 0);
      a = __builtin_amdgcn_mfma_f32_16x16x32_f16(wrec32[mt][1], hbB, a, 0, 0, 0);
      acc[mt] = a;
    }
    __builtin_amdgcn_s_setprio(0);
    // pack pre into two f16x8 halves (acc IS pre: bias was C-init)
    HS8 preA, preB;
#pragma unroll
    for (int mt = 0; mt < 2; ++mt) {
      preA.p[mt * 2] = pk2(acc[mt][0], acc[mt][1]);
      preA.p[mt * 2 + 1] = pk2(acc[mt][2], acc[mt][3]);
      preB.p[mt * 2] = pk2(acc[2 + mt][0], acc[2 + mt][1]);
      preB.p[mt * 2 + 1] = pk2(acc[2 + mt][2], acc[2 + mt][3]);
    }
    // variance: pair-merged squares -> ONE ones-MFMA (K-sum = cross-lane reduce)
    const f16x8 sq8 = __builtin_elementwise_fma(preB.v, preB.v, preA.v * preA.v);
    f32x4 sv = {0.f, 0.f, 0.f, 0.f};
    sv = __builtin_amdgcn_mfma_f32_16x16x32_f16(ones8, sq8, sv, 0, 0, 0);
    const float rstd = rsq_fast(fmaf(sv[0], inv64, LNEPS));
    const f16x8 rstd8 = bcast8(pk2(rstd, rstd));
    // LN + Pade tanh on f16x8 vectors
    const f16x8 uA = __builtin_elementwise_fma(preA.v * rstd8, lnwA, lnbA);
    const f16x8 uB = __builtin_elementwise_fma(preB.v * rstd8, lnwB, lnbB);
    const f16x8 xA = uA * uA;
    const f16x8 xB = uB * uB;
    HS8 nmA, nmB, dsA, dsB;
    nmA.v = uA * __builtin_elementwise_fma(xA, cNq8, cNl8);
    nmB.v = uB * __builtin_elementwise_fma(xB, cNq8, cNl8);
    dsA.v = __builtin_elementwise_fma(xA, cDq8, cDl8);
    dsB.v = __builtin_elementwise_fma(xB, cDq8, cDl8);
    // paired-denominator rcp per f16x2 pair (1 rcph per 2 elements)
    HS8 ttA, ttB;
#pragma unroll
    for (int i = 0; i < 4; ++i) {
      {
        const f16x2v ds = dsA.p[i];
        const f16x2v sw = __builtin_shufflevector(ds, ds, 1, 0);
        const _Float16 rD = __builtin_amdgcn_rcph(ds[0] * ds[1]);
        f16x2v rdv;
        rdv[0] = rD;
        rdv[1] = rD;
        ttA.p[i] = (nmA.p[i] * sw) * rdv;
      }
      {
        const f16x2v ds = dsB.p[i];
        const f16x2v sw = __builtin_shufflevector(ds, ds, 1, 0);
        const _Float16 rD = __builtin_amdgcn_rcph(ds[0] * ds[1]);
        f16x2v rdv;
        rdv[0] = rD;
        rdv[1] = rD;
        ttB.p[i] = (nmB.p[i] * sw) * rdv;
      }
    }
    f16x8 tA = __builtin_elementwise_min(ttA.v, cP8);
    f16x8 tB = __builtin_elementwise_min(ttB.v, cP8);
    tA = __builtin_elementwise_max(tA, cM8);
    tB = __builtin_elementwise_max(tB, cM8);
    // no +/-10 clamp: |h| <= 0.1/(1-dec) = softplus(tau) ~ 1.31 << 10
    hbA = __builtin_elementwise_fma(hbA, decA, tA);
    hbB = __builtin_elementwise_fma(hbB, decB, tB);
    xt = xtn;
  }

  // ================= Phase 2: x^T = Wx0 @ h^T + bx0 =================
  float xs[16];
#pragma unroll
  for (int mt = 0; mt < 4; ++mt) {
    const float4 b4 = *(const float4*)&bx0[mt * 16 + 4 * g];
    f32x4 a = {b4.x, b4.y, b4.z, b4.w};
#pragma unroll
    for (int kt = 0; kt < 2; ++kt) {
      const float4 w0 = *(const float4*)&Wx0[(mt * 16 + c) * HH + kt * 32 + 4 * g];
      const float4 w1 = *(const float4*)&Wx0[(mt * 16 + c) * HH + kt * 32 + 16 + 4 * g];
      const f16x8 wf = pack8(w0.x, w0.y, w0.z, w0.w, w1.x, w1.y, w1.z, w1.w);
      a = __builtin_amdgcn_mfma_f32_16x16x32_f16(wf, (kt == 0) ? hbA : hbB, a, 0, 0, 0);
    }
#pragma unroll
    for (int r = 0; r < 4; ++r) xs[mt * 4 + r] = a[r];
  }
  f16x8 xb8[2];
  xb8[0] = pack8(xs[0], xs[1], xs[2], xs[3], xs[4], xs[5], xs[6], xs[7]);
  xb8[1] = pack8(xs[8], xs[9], xs[10], xs[11], xs[12], xs[13], xs[14], xs[15]);

  // ---- y^T B-fragments (K=128 padded, phi slot order) ----
  f16x8 yf8[4];
#pragma unroll
  for (int kt = 0; kt < 4; ++kt) {
    float v[8];
#pragma unroll
    for (int j = 0; j < 8; ++j) {
      const int t = kt * 32 + ((j < 4) ? (4 * g + j) : (16 + 4 * g + (j - 4)));
      v[j] = (t < WIN) ? ybuf[c][t] : 0.f;
    }
    yf8[kt] = pack8(v[0], v[1], v[2], v[3], v[4], v[5], v[6], v[7]);
  }

  // ================= Phase 3: ISTA (Jacobi) =================
  for (int k = 0; k < KITER; ++k) {
    f32x4 z[4];
#pragma unroll
    for (int mt = 0; mt < 4; ++mt) {
      const float4 be4 = *(const float4*)&be[k * AA + mt * 16 + 4 * g];
      f32x4 a = {be4.x, be4.y, be4.z, be4.w};
      const int baseWe = (((k * 4 + mt) * 4) * 64 + l) * 8;
#pragma unroll
      for (int kt = 0; kt < 4; ++kt) {
        const f16x8 wf = *(const f16x8*)&we16[baseWe + kt * 512];
        a = __builtin_amdgcn_mfma_f32_16x16x32_f16(wf, yf8[kt], a, 0, 0, 0);
      }
      const int baseWr = (((k * 4 + mt) * 2) * 64 + l) * 8;
#pragma unroll
      for (int kt = 0; kt < 2; ++kt) {
        const f16x8 wf = *(const f16x8*)&wr16[baseWr + kt * 512];
        a = __builtin_amdgcn_mfma_f32_16x16x32_f16(wf, xb8[kt], a, 0, 0, 0);
      }
      z[mt] = a;
    }
#pragma unroll
    for (int mt = 0; mt < 4; ++mt) {
      const float4 lm4 = *(const float4*)&lamp[k * AA + mt * 16 + 4 * g];
      float xv[4];
#pragma unroll
      for (int r = 0; r < 4; ++r) {
        const float zz = z[mt][r];
        const float v = fmaxf(fabsf(zz) - (&lm4.x)[r], 0.0f);
        xv[r] = copysignf(v, zz);
        xs[mt * 4 + r] = xv[r];
      }
    }
    xb8[0] = pack8(xs[0], xs[1], xs[2], xs[3], xs[4], xs[5], xs[6], xs[7]);
    xb8[1] = pack8(xs[8], xs[9], xs[10], xs[11], xs[12], xs[13], xs[14], xs[15]);
  }

  // ================= Phase 4: outputs =================
  float* __restrict__ outp = out;               // power (B, 4)
  float* __restrict__ outx = out + NB * NAPPC;  // x (B, 64)
#pragma unroll
  for (int mt = 0; mt < 4; ++mt) {
    float4 v;
#pragma unroll
    for (int r = 0; r < 4; ++r) (&v.x)[r] = xs[mt * 4 + r];
    *(float4*)&outx[(s0 + c) * AA + mt * 16 + 4 * g] = v;
  }

  float P[4];
#pragma unroll
  for (int p = 0; p < NAPPC; ++p) {
    float acc = 0.f;
#pragma unroll
    for (int mt = 0; mt < 4; ++mt) {
      const float4 hw = *(const float4*)&head_W[p * AA + mt * 16 + 4 * g];
#pragma unroll
      for (int r = 0; r < 4; ++r) acc = fmaf(xs[mt * 4 + r], (&hw.x)[r], acc);
    }
    acc = xreduce(acc);
    P[p] = acc + head_b[p];
  }
  if (g == 0) {
    float4 pv;
#pragma unroll
    for (int p = 0; p < 4; ++p) (&pv.x)[p] = P[p];
    *(float4*)&outp[(s0 + c) * NAPPC] = pv;
  }
}

extern "C" void kernel_launch(void* const* d_in, const int* in_sizes, int n_in,
                              void* d_out, int out_size, void* d_ws, size_t ws_size,
                              hipStream_t stream) {
  const float* y         = (const float*)d_in[0];
  const float* w_in      = (const float*)d_in[1];
  const float* b_in      = (const float*)d_in[2];
  const float* tau_param = (const float*)d_in[3];
  const float* W_rec     = (const float*)d_in[4];
  const float* ln_w      = (const float*)d_in[5];
  const float* ln_b      = (const float*)d_in[6];
  const float* Wx0       = (const float*)d_in[7];
  const float* bx0       = (const float*)d_in[8];
  const float* We        = (const float*)d_in[9];
  const float* be        = (const float*)d_in[10];
  const float* Wr        = (const float*)d_in[11];
  const float* thr       = (const float*)d_in[12];
  const float* head_W    = (const float*)d_in[13];
  const float* head_b    = (const float*)d_in[14];

  pinn_prep<<<dim3(90), dim3(256), 0, stream>>>(
      W_rec, w_in, b_in, tau_param, thr, We, Wr, (char*)d_ws);
  pinn_fused<<<dim3(NB / 16), dim3(64), 0, stream>>>(
      y, ln_w, ln_b, Wx0, bx0, be, head_W, head_b, (const char*)d_ws,
      (float*)d_out);
}

// Round 19
// 91.871 us; speedup vs baseline: 1.0143x; 1.0143x over previous
//
#include <hip/hip_runtime.h>

// Fully-fused PINN-LISTA, transposed-MFMA + prep prefold + packed-f16 scan.
// R19 = exact revert to R17 (best: 91.96us). R18's glue-elimination +
// setprio regressed (-1.3%) -> locked in R17 as the optimum.
// R17 = (1) C-init via packed v_pk_fma_f32, (2) single variance ones-MFMA
// (squares pair-merged with pk_fma), (3) scan unrolled x4, on top of the
// K=32 MFMA shape + Pade tanh + paired-denominator rcp pipeline.

#define NB 32768
#define WIN 100
#define HH 64
#define AA 64
#define KITER 8
#define NAPPC 4
#define LNEPS 1e-5f
#define DTC 0.1f

// d_ws byte offsets
#define WS_WREC 0        // f16 [4][2][64][8]      = 8192 B   (A-slots, phi order)
#define WS_WE   8192     // f16 [8][4][4][64][8]   = 131072 B (K padded 100->128)
#define WS_WR   139264   // f16 [8][4][2][64][8]   = 65536 B
#define WS_WC   204800   // f32 [64]
#define WS_BC   205056   // f32 [64]
#define WS_DEC  205312   // f32 [64]
#define WS_LAM  205568   // f32 [8][64] -> ends 207616

typedef _Float16 f16x8 __attribute__((ext_vector_type(8)));
typedef _Float16 f16x4 __attribute__((ext_vector_type(4)));
typedef _Float16 f16x2v __attribute__((ext_vector_type(2)));
typedef __fp16 fp16x2 __attribute__((ext_vector_type(2)));
typedef float f32x4 __attribute__((ext_vector_type(4)));
typedef float f32x2 __attribute__((ext_vector_type(2)));

union H4 { f16x4 v; fp16x2 h[2]; };
union HS8 { f16x2v p[4]; f16x8 v; };
union FD { f16x2v h; fp16x2 u; };

__device__ __forceinline__ float exp2_fast(float x) { return __builtin_amdgcn_exp2f(x); }
__device__ __forceinline__ float rsq_fast(float x) { return __builtin_amdgcn_rsqf(x); }
__device__ __forceinline__ float log2_fast(float x) { return __builtin_amdgcn_logf(x); }
__device__ __forceinline__ float softplus_fast(float x) {
  float ax = fabsf(x);
  float e = exp2_fast(-ax * 1.4426950408889634f);
  return fmaxf(x, 0.0f) + log2_fast(1.0f + e) * 0.6931471805599453f;
}
__device__ __forceinline__ f16x2v pk2(float a, float b) {
  FD t;
  t.u = __builtin_amdgcn_cvt_pkrtz(a, b);
  return t.h;
}
__device__ __forceinline__ f16x4 pack4(float a, float b, float c2, float d) {
  H4 t;
  t.h[0] = __builtin_amdgcn_cvt_pkrtz(a, b);
  t.h[1] = __builtin_amdgcn_cvt_pkrtz(c2, d);
  return t.v;
}
__device__ __forceinline__ f16x8 pack8(float a, float b, float c2, float d,
                                       float e, float f, float g2, float h) {
  HS8 t;
  t.p[0] = pk2(a, b);
  t.p[1] = pk2(c2, d);
  t.p[2] = pk2(e, f);
  t.p[3] = pk2(g2, h);
  return t.v;
}
// cross-lane sum over lanes {i^16, i^32} (epilogue only)
__device__ __forceinline__ float xreduce(float q) {
  q += __shfl_xor(q, 16);
  q += __shfl_xor(q, 32);
  return q;
}

// ======================= prep kernel =======================
__global__ __launch_bounds__(256) void pinn_prep(
    const float* __restrict__ W_rec, const float* __restrict__ w_in,
    const float* __restrict__ b_in, const float* __restrict__ tau,
    const float* __restrict__ thr, const float* __restrict__ We,
    const float* __restrict__ Wr, char* __restrict__ ws) {
  _Float16* wrec16 = (_Float16*)(ws + WS_WREC);
  _Float16* we16 = (_Float16*)(ws + WS_WE);
  _Float16* wr16 = (_Float16*)(ws + WS_WR);
  float* wc = (float*)(ws + WS_WC);
  float* bc = (float*)(ws + WS_BC);
  float* dec = (float*)(ws + WS_DEC);
  float* lam = (float*)(ws + WS_LAM);
  const int tid = threadIdx.x, bid = blockIdx.x;
  if (bid == 0) {
    __shared__ float rm[64];
    if (tid < 64) {
      float s = 0.f;
      for (int m = 0; m < 64; ++m) s += W_rec[tid * 64 + m];
      rm[tid] = s * (1.f / 64.f);
    }
    __syncthreads();
    // wrec A-slots: idx = ((mt*2+kt)*64+l)*8+j
    for (int idx = tid; idx < 4096; idx += 256) {
      const int j = idx & 7, l = (idx >> 3) & 63, kt = (idx >> 9) & 1, mt = idx >> 10;
      const int g4 = ((l >> 4) << 2);
      const int k_in = kt * 32 + ((j < 4) ? (g4 + j) : (16 + g4 + (j - 4)));
      const int m = mt * 16 + (l & 15);
      wrec16[idx] = (_Float16)(W_rec[k_in * 64 + m] - rm[k_in]);
    }
    if (tid < 64) {
      float sw = 0.f, sb = 0.f;
      for (int i = 0; i < 64; ++i) { sw += w_in[i]; sb += b_in[i]; }
      wc[tid] = w_in[tid] - sw * (1.f / 64.f);
      bc[tid] = b_in[tid] - sb * (1.f / 64.f);
      dec[tid] = 1.f - DTC / softplus_fast(tau[tid]);
    }
    for (int i = tid; i < 512; i += 256) lam[i] = softplus_fast(thr[i]);
  } else {
    const int stride = (gridDim.x - 1) * 256;
    for (int i = (bid - 1) * 256 + tid; i < 65536 + 32768; i += stride) {
      if (i < 65536) {
        // we A-slots: i = (((k*4+mt)*4+kt)*64+l)*8+j
        const int j = i & 7, l = (i >> 3) & 63, kt = (i >> 9) & 3, mt = (i >> 11) & 3, k = i >> 13;
        const int g4 = ((l >> 4) << 2);
        const int t = kt * 32 + ((j < 4) ? (g4 + j) : (16 + g4 + (j - 4)));
        const int row = k * 64 + mt * 16 + (l & 15);
        we16[i] = (t < WIN) ? (_Float16)We[row * WIN + t] : (_Float16)0.f;
      } else {
        // wr A-slots: i2 = (((k*4+mt)*2+kt)*64+l)*8+j
        const int i2 = i - 65536;
        const int j = i2 & 7, l = (i2 >> 3) & 63, kt = (i2 >> 9) & 1, mt = (i2 >> 10) & 3, k = i2 >> 12;
        const int g4 = ((l >> 4) << 2);
        const int k_in = kt * 32 + ((j < 4) ? (g4 + j) : (16 + g4 + (j - 4)));
        const int row = k * 64 + mt * 16 + (l & 15);
        wr16[i2] = (_Float16)Wr[row * 64 + k_in];
      }
    }
  }
}

// ======================= main kernel =======================
__global__ __attribute__((amdgpu_flat_work_group_size(64, 64),
                          amdgpu_waves_per_eu(2, 2))) void pinn_fused(
    const float* __restrict__ y, const float* __restrict__ ln_w,
    const float* __restrict__ ln_b, const float* __restrict__ Wx0,
    const float* __restrict__ bx0, const float* __restrict__ be,
    const float* __restrict__ head_W, const float* __restrict__ head_b,
    const char* __restrict__ ws, float* __restrict__ out) {
  __shared__ float ybuf[16][101];  // (c*101)%32 all distinct -> conflict-free columns

  const _Float16* wrec16 = (const _Float16*)(ws + WS_WREC);
  const _Float16* we16 = (const _Float16*)(ws + WS_WE);
  const _Float16* wr16 = (const _Float16*)(ws + WS_WR);
  const float* wcp = (const float*)(ws + WS_WC);
  const float* bcp = (const float*)(ws + WS_BC);
  const float* decp = (const float*)(ws + WS_DEC);
  const float* lamp = (const float*)(ws + WS_LAM);

  const int l = threadIdx.x;
  const int c = l & 15;  // sample (C col / B col / A row)
  const int g = l >> 4;  // lane group
  const int s0 = blockIdx.x * 16;

  // ---- stage y tile ----
  for (int i = l; i < 16 * WIN; i += 64) {
    const int s = i / WIN;
    ybuf[s][i - s * WIN] = y[s0 * WIN + i];
  }

  // ---- per-H constants: bias in f32x2 (packed C-init), LN/decay as f16x2 ----
  f32x2 wcf2[8], bcf2[8];
  f16x2v lnw2[8], lnb2[8], dec2[8];
#pragma unroll
  for (int mt = 0; mt < 4; ++mt) {
    const int hb4 = mt * 16 + g * 4;
    const float4 wi = *(const float4*)&wcp[hb4];
    const float4 bi = *(const float4*)&bcp[hb4];
    const float4 lw = *(const float4*)&ln_w[hb4];
    const float4 lb = *(const float4*)&ln_b[hb4];
    const float4 dc = *(const float4*)&decp[hb4];
    wcf2[mt * 2] = (f32x2){wi.x, wi.y};
    wcf2[mt * 2 + 1] = (f32x2){wi.z, wi.w};
    bcf2[mt * 2] = (f32x2){bi.x, bi.y};
    bcf2[mt * 2 + 1] = (f32x2){bi.z, bi.w};
    lnw2[mt * 2] = pk2(lw.x, lw.y);
    lnw2[mt * 2 + 1] = pk2(lw.z, lw.w);
    lnb2[mt * 2] = pk2(lb.x, lb.y);
    lnb2[mt * 2 + 1] = pk2(lb.z, lb.w);
    dec2[mt * 2] = pk2(dc.x, dc.y);
    dec2[mt * 2 + 1] = pk2(dc.z, dc.w);
  }

  // ---- centered W' A-fragments (K=32 slot order) ----
  f16x8 wrec32[4][2];
#pragma unroll
  for (int mt = 0; mt < 4; ++mt)
#pragma unroll
    for (int kt = 0; kt < 2; ++kt)
      wrec32[mt][kt] = *(const f16x8*)&wrec16[((mt * 2 + kt) * 64 + l) * 8];

  __syncthreads();  // ybuf ready

  // h state: hs2[i] f16x2 pairs; B-frags = concat(hs2[0..3]) / concat(hs2[4..7])
  f16x2v hs2[8];
#pragma unroll
  for (int i = 0; i < 8; ++i) hs2[i] = pk2(0.f, 0.f);
  f16x8 hbA, hbB;
  {
    HS8 u0, u1;
    u0.p[0] = hs2[0]; u0.p[1] = hs2[1]; u0.p[2] = hs2[2]; u0.p[3] = hs2[3];
    u1.p[0] = hs2[4]; u1.p[1] = hs2[5]; u1.p[2] = hs2[6]; u1.p[3] = hs2[7];
    hbA = u0.v;
    hbB = u1.v;
  }
  const float inv64 = 1.0f / 64.0f;

  // Pade (1/16-scaled) / clamp constants + ones A-fragment for the reduce-MFMA
  const f16x2v cNq = pk2(0.00625f, 0.00625f);   // 0.1/16
  const f16x2v cNl = pk2(0.09375f, 0.09375f);   // 1.5/16
  const f16x2v cDq = pk2(0.375f, 0.375f);       // 6/16
  const f16x2v cDl = pk2(0.9375f, 0.9375f);     // 15/16
  const f16x2v cP = pk2(0.1f, 0.1f);
  const f16x2v cM = pk2(-0.1f, -0.1f);
  const f16x8 ones8 = pack8(1.f, 1.f, 1.f, 1.f, 1.f, 1.f, 1.f, 1.f);

  // ================= Phase 1: 100-step scan =================
  float xt = ybuf[c][0];
#pragma unroll 4
  for (int t = 0; t < WIN; ++t) {
    const float xtn = ybuf[c][t + 1];  // col 100 in-bounds (padded), unused at t=99
    const f32x2 xt2 = {xt, xt};
    f32x4 acc[4];
#pragma unroll
    for (int mt = 0; mt < 4; ++mt) {
      const f32x2 a01 = __builtin_elementwise_fma(xt2, wcf2[mt * 2], bcf2[mt * 2]);
      const f32x2 a23 = __builtin_elementwise_fma(xt2, wcf2[mt * 2 + 1], bcf2[mt * 2 + 1]);
      f32x4 a = {a01[0], a01[1], a23[0], a23[1]};
      a = __builtin_amdgcn_mfma_f32_16x16x32_f16(wrec32[mt][0], hbA, a, 0, 0, 0);
      a = __builtin_amdgcn_mfma_f32_16x16x32_f16(wrec32[mt][1], hbB, a, 0, 0, 0);
      acc[mt] = a;
    }
    // pre pairs (acc IS pre: bias was C-init)
    f16x2v pre2[8];
#pragma unroll
    for (int mt = 0; mt < 4; ++mt) {
      pre2[mt * 2] = pk2(acc[mt][0], acc[mt][1]);
      pre2[mt * 2 + 1] = pk2(acc[mt][2], acc[mt][3]);
    }
    // variance: pair-merged squares -> ONE ones-MFMA (K-sum = cross-lane reduce)
    HS8 sq;
#pragma unroll
    for (int i = 0; i < 4; ++i)
      sq.p[i] = __builtin_elementwise_fma(pre2[4 + i], pre2[4 + i], pre2[i] * pre2[i]);
    f32x4 sv = {0.f, 0.f, 0.f, 0.f};
    sv = __builtin_amdgcn_mfma_f32_16x16x32_f16(ones8, sq.v, sv, 0, 0, 0);
    const float rstd = rsq_fast(fmaf(sv[0], inv64, LNEPS));
    const f16x2v rstdv = pk2(rstd, rstd);
#pragma unroll
    for (int i = 0; i < 8; ++i) {
      const f16x2v u = __builtin_elementwise_fma(pre2[i] * rstdv, lnw2[i], lnb2[i]);
      const f16x2v x2 = u * u;
      const f16x2v nm = u * __builtin_elementwise_fma(x2, cNq, cNl);  // num/16
      const f16x2v ds = __builtin_elementwise_fma(x2, cDq, cDl);      // den/16
      const f16x2v sw = __builtin_shufflevector(ds, ds, 1, 0);
      const f16x2v Dp = ds * sw;                                      // both = d0*d1
      const _Float16 rD = __builtin_amdgcn_rcph(Dp[0]);
      f16x2v rdv;
      rdv[0] = rD;
      rdv[1] = rD;
      f16x2v tt = (nm * sw) * rdv;  // num_i * den_{1-i} / (d0*d1) = num_i/den_i
      tt = __builtin_elementwise_min(tt, cP);
      tt = __builtin_elementwise_max(tt, cM);
      // no +/-10 clamp: |h| <= 0.1/(1-dec) = softplus(tau) ~ 1.31 << 10
      hs2[i] = __builtin_elementwise_fma(hs2[i], dec2[i], tt);
    }
    {
      HS8 u0, u1;
      u0.p[0] = hs2[0]; u0.p[1] = hs2[1]; u0.p[2] = hs2[2]; u0.p[3] = hs2[3];
      u1.p[0] = hs2[4]; u1.p[1] = hs2[5]; u1.p[2] = hs2[6]; u1.p[3] = hs2[7];
      hbA = u0.v;
      hbB = u1.v;
    }
    xt = xtn;
  }

  // ================= Phase 2: x^T = Wx0 @ h^T + bx0 =================
  float xs[16];
#pragma unroll
  for (int mt = 0; mt < 4; ++mt) {
    const float4 b4 = *(const float4*)&bx0[mt * 16 + 4 * g];
    f32x4 a = {b4.x, b4.y, b4.z, b4.w};
#pragma unroll
    for (int kt = 0; kt < 2; ++kt) {
      const float4 w0 = *(const float4*)&Wx0[(mt * 16 + c) * HH + kt * 32 + 4 * g];
      const float4 w1 = *(const float4*)&Wx0[(mt * 16 + c) * HH + kt * 32 + 16 + 4 * g];
      const f16x8 wf = pack8(w0.x, w0.y, w0.z, w0.w, w1.x, w1.y, w1.z, w1.w);
      a = __builtin_amdgcn_mfma_f32_16x16x32_f16(wf, (kt == 0) ? hbA : hbB, a, 0, 0, 0);
    }
#pragma unroll
    for (int r = 0; r < 4; ++r) xs[mt * 4 + r] = a[r];
  }
  f16x8 xb8[2];
  xb8[0] = pack8(xs[0], xs[1], xs[2], xs[3], xs[4], xs[5], xs[6], xs[7]);
  xb8[1] = pack8(xs[8], xs[9], xs[10], xs[11], xs[12], xs[13], xs[14], xs[15]);

  // ---- y^T B-fragments (K=128 padded, phi slot order) ----
  f16x8 yf8[4];
#pragma unroll
  for (int kt = 0; kt < 4; ++kt) {
    float v[8];
#pragma unroll
    for (int j = 0; j < 8; ++j) {
      const int t = kt * 32 + ((j < 4) ? (4 * g + j) : (16 + 4 * g + (j - 4)));
      v[j] = (t < WIN) ? ybuf[c][t] : 0.f;
    }
    yf8[kt] = pack8(v[0], v[1], v[2], v[3], v[4], v[5], v[6], v[7]);
  }

  // ================= Phase 3: ISTA (Jacobi) =================
  for (int k = 0; k < KITER; ++k) {
    f32x4 z[4];
#pragma unroll
    for (int mt = 0; mt < 4; ++mt) {
      const float4 be4 = *(const float4*)&be[k * AA + mt * 16 + 4 * g];
      f32x4 a = {be4.x, be4.y, be4.z, be4.w};
      const int baseWe = (((k * 4 + mt) * 4) * 64 + l) * 8;
#pragma unroll
      for (int kt = 0; kt < 4; ++kt) {
        const f16x8 wf = *(const f16x8*)&we16[baseWe + kt * 512];
        a = __builtin_amdgcn_mfma_f32_16x16x32_f16(wf, yf8[kt], a, 0, 0, 0);
      }
      const int baseWr = (((k * 4 + mt) * 2) * 64 + l) * 8;
#pragma unroll
      for (int kt = 0; kt < 2; ++kt) {
        const f16x8 wf = *(const f16x8*)&wr16[baseWr + kt * 512];
        a = __builtin_amdgcn_mfma_f32_16x16x32_f16(wf, xb8[kt], a, 0, 0, 0);
      }
      z[mt] = a;
    }
#pragma unroll
    for (int mt = 0; mt < 4; ++mt) {
      const float4 lm4 = *(const float4*)&lamp[k * AA + mt * 16 + 4 * g];
      float xv[4];
#pragma unroll
      for (int r = 0; r < 4; ++r) {
        const float zz = z[mt][r];
        const float v = fmaxf(fabsf(zz) - (&lm4.x)[r], 0.0f);
        xv[r] = copysignf(v, zz);
        xs[mt * 4 + r] = xv[r];
      }
    }
    xb8[0] = pack8(xs[0], xs[1], xs[2], xs[3], xs[4], xs[5], xs[6], xs[7]);
    xb8[1] = pack8(xs[8], xs[9], xs[10], xs[11], xs[12], xs[13], xs[14], xs[15]);
  }

  // ================= Phase 4: outputs =================
  float* __restrict__ outp = out;               // power (B, 4)
  float* __restrict__ outx = out + NB * NAPPC;  // x (B, 64)
#pragma unroll
  for (int mt = 0; mt < 4; ++mt) {
    float4 v;
#pragma unroll
    for (int r = 0; r < 4; ++r) (&v.x)[r] = xs[mt * 4 + r];
    *(float4*)&outx[(s0 + c) * AA + mt * 16 + 4 * g] = v;
  }

  float P[4];
#pragma unroll
  for (int p = 0; p < NAPPC; ++p) {
    float acc = 0.f;
#pragma unroll
    for (int mt = 0; mt < 4; ++mt) {
      const float4 hw = *(const float4*)&head_W[p * AA + mt * 16 + 4 * g];
#pragma unroll
      for (int r = 0; r < 4; ++r) acc = fmaf(xs[mt * 4 + r], (&hw.x)[r], acc);
    }
    acc = xreduce(acc);
    P[p] = acc + head_b[p];
  }
  if (g == 0) {
    float4 pv;
#pragma unroll
    for (int p = 0; p < 4; ++p) (&pv.x)[p] = P[p];
    *(float4*)&outp[(s0 + c) * NAPPC] = pv;
  }
}

extern "C" void kernel_launch(void* const* d_in, const int* in_sizes, int n_in,
                              void* d_out, int out_size, void* d_ws, size_t ws_size,
                              hipStream_t stream) {
  const float* y         = (const float*)d_in[0];
  const float* w_in      = (const float*)d_in[1];
  const float* b_in      = (const float*)d_in[2];
  const float* tau_param = (const float*)d_in[3];
  const float* W_rec     = (const float*)d_in[4];
  const float* ln_w      = (const float*)d_in[5];
  const float* ln_b      = (const float*)d_in[6];
  const float* Wx0       = (const float*)d_in[7];
  const float* bx0       = (const float*)d_in[8];
  const float* We        = (const float*)d_in[9];
  const float* be        = (const float*)d_in[10];
  const float* Wr        = (const float*)d_in[11];
  const float* thr       = (const float*)d_in[12];
  const float* head_W    = (const float*)d_in[13];
  const float* head_b    = (const float*)d_in[14];

  pinn_prep<<<dim3(90), dim3(256), 0, stream>>>(
      W_rec, w_in, b_in, tau_param, thr, We, Wr, (char*)d_ws);
  pinn_fused<<<dim3(NB / 16), dim3(64), 0, stream>>>(
      y, ln_w, ln_b, Wx0, bx0, be, head_W, head_b, (const char*)d_ws,
      (float*)d_out);
}